// Round 1
// baseline (783.654 us; speedup 1.0000x reference)
//
#include <hip/hip_runtime.h>
#include <cmath>

#define EPSF 1.1920928955078125e-07f

constexpr int BB = 8192;
constexpr int MZ = 2000;
constexpr int NF = 2048;
constexpr float W_INT = 0.1f, W_PROB = 0.3f, W_WS = 0.5f, W_MORGAN = 0.1f;
constexpr float POS_W = 5.0f;

// acc layout (doubles in d_ws):
// 0: prob bce*w sum   1: intensity sq sum   2: iw sum
// 3: ws per_sample*valid sum   4: nvalid   5: morgan bce sum

__device__ inline float waveReduce(float v) {
#pragma unroll
  for (int off = 32; off > 0; off >>= 1) v += __shfl_down(v, off, 64);
  return v;
}

__device__ inline float bceLogits(float x, float y) {
  return fmaxf(x, 0.f) - x * y + log1pf(expf(-fabsf(x)));
}

__global__ void init_acc_kernel(double* acc) {
  if (threadIdx.x < 8) acc[threadIdx.x] = 0.0;
}

__global__ __launch_bounds__(256) void row_kernel(
    const float* __restrict__ pi, const float* __restrict__ pl,
    const float* __restrict__ ti, const float* __restrict__ tp,
    double* __restrict__ acc) {
  __shared__ float red[4][5];
  __shared__ float tot[5];
  __shared__ float s_scan[256];

  const int tid = threadIdx.x;
  const int lane = tid & 63;
  const int wid = tid >> 6;
  const long base = (long)blockIdx.x * MZ;
  const int i0 = tid * 8;

  float a[8], b[8];
  float s_bce = 0.f, s_sq = 0.f, s_iw = 0.f, la = 0.f, lb = 0.f;

  if (i0 + 8 <= MZ) {  // MZ = 250*8: threads 0..249 full vector path
    const float4* ppi = (const float4*)(pi + base + i0);
    const float4* ppl = (const float4*)(pl + base + i0);
    const float4* pti = (const float4*)(ti + base + i0);
    const float4* ptp = (const float4*)(tp + base + i0);
    float4 vpi0 = ppi[0], vpi1 = ppi[1];
    float4 vpl0 = ppl[0], vpl1 = ppl[1];
    float4 vti0 = pti[0], vti1 = pti[1];
    float4 vtp0 = ptp[0], vtp1 = ptp[1];
    float xpi[8] = {vpi0.x, vpi0.y, vpi0.z, vpi0.w, vpi1.x, vpi1.y, vpi1.z, vpi1.w};
    float xpl[8] = {vpl0.x, vpl0.y, vpl0.z, vpl0.w, vpl1.x, vpl1.y, vpl1.z, vpl1.w};
    float xti[8] = {vti0.x, vti0.y, vti0.z, vti0.w, vti1.x, vti1.y, vti1.z, vti1.w};
    float xtp[8] = {vtp0.x, vtp0.y, vtp0.z, vtp0.w, vtp1.x, vtp1.y, vtp1.z, vtp1.w};
#pragma unroll
    for (int j = 0; j < 8; ++j) {
      const float x = xpl[j];
      const float y = xtp[j];
      const float em = expf(-fabsf(x));   // e^{-|x|}, shared by bce + sigmoid
      const float bce = fmaxf(x, 0.f) - x * y + log1pf(em);
      const bool pos = (y > 0.5f);
      s_bce += bce * (pos ? POS_W : 1.f);
      const float d = xpi[j] - xti[j];
      if (pos) { s_sq = fmaf(d, d, s_sq); s_iw += 1.f; }
      const float sig = (x >= 0.f) ? (1.f / (1.f + em)) : (em / (1.f + em));
      const float av = fmaxf(xpi[j], 0.f) * sig;
      const float bv = xti[j] * y;
      a[j] = av; b[j] = bv;
      la += av; lb += bv;
    }
  } else {
#pragma unroll
    for (int j = 0; j < 8; ++j) { a[j] = 0.f; b[j] = 0.f; }
  }

  // fused block-reduce of 5 partials
  float v0 = waveReduce(la);
  float v1 = waveReduce(lb);
  float v2 = waveReduce(s_bce);
  float v3 = waveReduce(s_sq);
  float v4 = waveReduce(s_iw);
  if (lane == 0) {
    red[wid][0] = v0; red[wid][1] = v1; red[wid][2] = v2;
    red[wid][3] = v3; red[wid][4] = v4;
  }
  __syncthreads();
  if (tid == 0) {
#pragma unroll
    for (int k = 0; k < 5; ++k)
      tot[k] = red[0][k] + red[1][k] + red[2][k] + red[3][k];
  }
  __syncthreads();
  const float s1 = tot[0], st1 = tot[1];
  if (tid == 0) {
    atomicAdd(&acc[0], (double)tot[2]);
    atomicAdd(&acc[1], (double)tot[3]);
    atomicAdd(&acc[2], (double)tot[4]);
  }

  // replicate jnp's double renormalization analytically
  const float s2 = s1 / (s1 + EPSF);
  const float scaleP = 1.f / ((s1 + EPSF) * (s2 + EPSF));
  const float st2 = st1 / (st1 + EPSF);
  const float scaleQ = 1.f / ((st1 + EPSF) * (st2 + EPSF));

  // in-register chunk prefix of (p - q)
  float run = 0.f;
#pragma unroll
  for (int j = 0; j < 8; ++j) {
    run += a[j] * scaleP - b[j] * scaleQ;
    a[j] = run;  // reuse a[] as inclusive chunk prefix
  }
  s_scan[tid] = run;
  __syncthreads();
  // Hillis-Steele inclusive scan over 256 chunk totals
  for (int off = 1; off < 256; off <<= 1) {
    float t = (tid >= off) ? s_scan[tid - off] : 0.f;
    __syncthreads();
    s_scan[tid] += t;
    __syncthreads();
  }
  const float excl = s_scan[tid] - run;

  // |cdf| sum, excluding last grid point (index MZ-1)
  float labs = 0.f;
#pragma unroll
  for (int j = 0; j < 8; ++j) {
    if (i0 + j < MZ - 1) labs += fabsf(excl + a[j]);
  }
  labs = waveReduce(labs);
  if (lane == 0) red[wid][0] = labs;
  __syncthreads();
  if (tid == 0) {
    const float t = red[0][0] + red[1][0] + red[2][0] + red[3][0];
    const float w1 = t * (1.f / (1999.0f + EPSF));
    const float psum = s2 / (s2 + EPSF);
    const float qsum = st2 / (st2 + EPSF);
    const float valid = (qsum > EPSF) ? 1.f : 0.f;
    const float per = (psum > EPSF) ? w1 : 1.f;
    atomicAdd(&acc[3], (double)(per * valid));
    atomicAdd(&acc[4], (double)valid);
  }
}

__global__ __launch_bounds__(256) void morgan_kernel(
    const float* __restrict__ x, const int* __restrict__ y,
    double* __restrict__ acc) {
  __shared__ float red[4];
  const long n4 = (long)BB * NF / 4;
  const long stride = (long)gridDim.x * blockDim.x;
  float ls = 0.f;
  for (long i = (long)blockIdx.x * blockDim.x + threadIdx.x; i < n4; i += stride) {
    const float4 xv = ((const float4*)x)[i];
    const int4 yv = ((const int4*)y)[i];
    ls += bceLogits(xv.x, (float)yv.x);
    ls += bceLogits(xv.y, (float)yv.y);
    ls += bceLogits(xv.z, (float)yv.z);
    ls += bceLogits(xv.w, (float)yv.w);
  }
  ls = waveReduce(ls);
  const int lane = threadIdx.x & 63, wid = threadIdx.x >> 6;
  if (lane == 0) red[wid] = ls;
  __syncthreads();
  if (threadIdx.x == 0)
    atomicAdd(&acc[5], (double)(red[0] + red[1] + red[2] + red[3]));
}

__global__ void finalize_kernel(const double* __restrict__ acc,
                                float* __restrict__ out) {
  if (threadIdx.x == 0 && blockIdx.x == 0) {
    const double prob = acc[0] / ((double)BB * (double)MZ);
    const double inten = acc[1] / (acc[2] + (double)EPSF);
    const double nv = acc[4];
    const double ws = (nv > 0.0) ? (acc[3] / fmax(nv, 1.0)) : 0.0;
    const double morgan = acc[5] / ((double)BB * (double)NF);
    double tot = (double)W_PROB * prob + (double)W_INT * inten +
                 (double)W_WS * ws + (double)W_MORGAN * morgan;
    float t = (float)tot;
    if (isnan(t) || isinf(t)) t = 100000.0f;
    out[0] = t;
  }
}

extern "C" void kernel_launch(void* const* d_in, const int* in_sizes, int n_in,
                              void* d_out, int out_size, void* d_ws, size_t ws_size,
                              hipStream_t stream) {
  const float* pred_int = (const float*)d_in[0];
  const float* pred_pl  = (const float*)d_in[1];
  const float* pred_mg  = (const float*)d_in[2];
  const float* true_int = (const float*)d_in[3];
  const float* true_pr  = (const float*)d_in[4];
  const int*   true_mg  = (const int*)d_in[5];
  double* acc = (double*)d_ws;

  init_acc_kernel<<<1, 64, 0, stream>>>(acc);
  row_kernel<<<BB, 256, 0, stream>>>(pred_int, pred_pl, true_int, true_pr, acc);
  morgan_kernel<<<2048, 256, 0, stream>>>(pred_mg, true_mg, acc);
  finalize_kernel<<<1, 64, 0, stream>>>(acc, (float*)d_out);
}

// Round 4
// 388.332 us; speedup vs baseline: 2.0180x; 2.0180x over previous
//
#include <hip/hip_runtime.h>
#include <cmath>

#define EPSF 1.1920928955078125e-07f

constexpr int BB = 8192;
constexpr int MZ = 2000;
constexpr int NF = 2048;
constexpr int MORGAN_BLOCKS = 2048;
constexpr float W_INT = 0.1f, W_PROB = 0.3f, W_WS = 0.5f, W_MORGAN = 0.1f;
constexpr float POS_W = 5.0f;

// d_ws layout (floats):
//   pb[k][row], k=0..4 : per-row partials  (5 * 8192)
//     k=0: bce*w sum   k=1: sq sum   k=2: iw sum   k=3: per*valid   k=4: valid
//   pbm[b], b=0..2047  : morgan per-block partial
constexpr int PB_STRIDE = BB;
constexpr int PBM_OFF = 5 * BB;

__device__ inline float waveReduce(float v) {
#pragma unroll
  for (int off = 32; off > 0; off >>= 1) v += __shfl_down(v, off, 64);
  return v;
}

__device__ inline double waveReduceD(double v) {
#pragma unroll
  for (int off = 32; off > 0; off >>= 1) v += __shfl_down(v, off, 64);
  return v;
}

__device__ inline float bceLogits(float x, float y) {
  return fmaxf(x, 0.f) - x * y + log1pf(expf(-fabsf(x)));
}

__global__ __launch_bounds__(256) void row_kernel(
    const float* __restrict__ pi, const float* __restrict__ pl,
    const float* __restrict__ ti, const float* __restrict__ tp,
    float* __restrict__ pb) {
  __shared__ float red[4][8];   // per-wave partials (5 used)
  __shared__ float bc[2];       // s1, st1 broadcast
  __shared__ float wtot[4];     // per-wave scan totals

  const int tid = threadIdx.x;
  const int lane = tid & 63;
  const int wid = tid >> 6;
  const int bid = blockIdx.x;
  const long base = (long)bid * MZ;
  const int i0 = tid * 8;

  float a[8], b[8];
  float s_bce = 0.f, s_sq = 0.f, s_iw = 0.f, la = 0.f, lb = 0.f;

  if (i0 + 8 <= MZ) {  // MZ = 250*8: threads 0..249 take the full vector path
    const float4* ppi = (const float4*)(pi + base + i0);
    const float4* ppl = (const float4*)(pl + base + i0);
    const float4* pti = (const float4*)(ti + base + i0);
    const float4* ptp = (const float4*)(tp + base + i0);
    float4 vpi0 = ppi[0], vpi1 = ppi[1];
    float4 vpl0 = ppl[0], vpl1 = ppl[1];
    float4 vti0 = pti[0], vti1 = pti[1];
    float4 vtp0 = ptp[0], vtp1 = ptp[1];
    float xpi[8] = {vpi0.x, vpi0.y, vpi0.z, vpi0.w, vpi1.x, vpi1.y, vpi1.z, vpi1.w};
    float xpl[8] = {vpl0.x, vpl0.y, vpl0.z, vpl0.w, vpl1.x, vpl1.y, vpl1.z, vpl1.w};
    float xti[8] = {vti0.x, vti0.y, vti0.z, vti0.w, vti1.x, vti1.y, vti1.z, vti1.w};
    float xtp[8] = {vtp0.x, vtp0.y, vtp0.z, vtp0.w, vtp1.x, vtp1.y, vtp1.z, vtp1.w};
#pragma unroll
    for (int j = 0; j < 8; ++j) {
      const float x = xpl[j];
      const float y = xtp[j];
      const float em = expf(-fabsf(x));   // e^{-|x|}, shared by bce + sigmoid
      const float bce = fmaxf(x, 0.f) - x * y + log1pf(em);
      const bool pos = (y > 0.5f);
      s_bce += bce * (pos ? POS_W : 1.f);
      const float d = xpi[j] - xti[j];
      if (pos) { s_sq = fmaf(d, d, s_sq); s_iw += 1.f; }
      const float sig = (x >= 0.f) ? (1.f / (1.f + em)) : (em / (1.f + em));
      const float av = fmaxf(xpi[j], 0.f) * sig;
      const float bv = xti[j] * y;
      a[j] = av; b[j] = bv;
      la += av; lb += bv;
    }
  } else {
#pragma unroll
    for (int j = 0; j < 8; ++j) { a[j] = 0.f; b[j] = 0.f; }
  }

  // fused block-reduce of 5 partials (1 barrier, shuffles otherwise)
  float v0 = waveReduce(la);
  float v1 = waveReduce(lb);
  float v2 = waveReduce(s_bce);
  float v3 = waveReduce(s_sq);
  float v4 = waveReduce(s_iw);
  if (lane == 0) {
    red[wid][0] = v0; red[wid][1] = v1; red[wid][2] = v2;
    red[wid][3] = v3; red[wid][4] = v4;
  }
  __syncthreads();
  if (tid == 0) {
    const float s1  = red[0][0] + red[1][0] + red[2][0] + red[3][0];
    const float st1 = red[0][1] + red[1][1] + red[2][1] + red[3][1];
    bc[0] = s1; bc[1] = st1;
    // write the three streaming partials now (plain stores, no atomics)
    pb[0 * PB_STRIDE + bid] = red[0][2] + red[1][2] + red[2][2] + red[3][2];
    pb[1 * PB_STRIDE + bid] = red[0][3] + red[1][3] + red[2][3] + red[3][3];
    pb[2 * PB_STRIDE + bid] = red[0][4] + red[1][4] + red[2][4] + red[3][4];
  }
  __syncthreads();
  const float s1 = bc[0], st1 = bc[1];

  // replicate jnp's double renormalization analytically
  const float s2 = s1 / (s1 + EPSF);
  const float scaleP = 1.f / ((s1 + EPSF) * (s2 + EPSF));
  const float st2 = st1 / (st1 + EPSF);
  const float scaleQ = 1.f / ((st1 + EPSF) * (st2 + EPSF));

  // in-register chunk prefix of (p - q)
  float run = 0.f;
#pragma unroll
  for (int j = 0; j < 8; ++j) {
    run += a[j] * scaleP - b[j] * scaleQ;
    a[j] = run;  // a[] now holds the inclusive chunk prefix
  }

  // per-wave inclusive scan of chunk totals (no barriers)
  float sc = run;
#pragma unroll
  for (int off = 1; off < 64; off <<= 1) {
    const float t = __shfl_up(sc, off, 64);
    if (lane >= off) sc += t;
  }
  if (lane == 63) wtot[wid] = sc;   // wave total
  __syncthreads();
  float woff = 0.f;
#pragma unroll
  for (int w = 0; w < 4; ++w) woff += (w < wid) ? wtot[w] : 0.f;
  const float excl = sc - run + woff;  // exclusive prefix for this thread

  // |cdf| sum, excluding last grid point (index MZ-1)
  float labs = 0.f;
#pragma unroll
  for (int j = 0; j < 8; ++j) {
    if (i0 + j < MZ - 1) labs += fabsf(excl + a[j]);
  }
  labs = waveReduce(labs);
  if (lane == 0) red[wid][0] = labs;
  __syncthreads();
  if (tid == 0) {
    const float t = red[0][0] + red[1][0] + red[2][0] + red[3][0];
    const float w1 = t * (1.f / (1999.0f + EPSF));
    const float psum = s2 / (s2 + EPSF);
    const float qsum = st2 / (st2 + EPSF);
    const float valid = (qsum > EPSF) ? 1.f : 0.f;
    const float per = (psum > EPSF) ? w1 : 1.f;
    pb[3 * PB_STRIDE + bid] = per * valid;
    pb[4 * PB_STRIDE + bid] = valid;
  }
}

__global__ __launch_bounds__(256) void morgan_kernel(
    const float* __restrict__ x, const int* __restrict__ y,
    float* __restrict__ pbm) {
  __shared__ float red[4];
  const long n4 = (long)BB * NF / 4;
  const long stride = (long)gridDim.x * blockDim.x;
  float ls = 0.f;
  for (long i = (long)blockIdx.x * blockDim.x + threadIdx.x; i < n4; i += stride) {
    const float4 xv = ((const float4*)x)[i];
    const int4 yv = ((const int4*)y)[i];
    ls += bceLogits(xv.x, (float)yv.x);
    ls += bceLogits(xv.y, (float)yv.y);
    ls += bceLogits(xv.z, (float)yv.z);
    ls += bceLogits(xv.w, (float)yv.w);
  }
  ls = waveReduce(ls);
  const int lane = threadIdx.x & 63, wid = threadIdx.x >> 6;
  if (lane == 0) red[wid] = ls;
  __syncthreads();
  if (threadIdx.x == 0)
    pbm[blockIdx.x] = red[0] + red[1] + red[2] + red[3];
}

__global__ __launch_bounds__(1024) void reduce_finalize_kernel(
    const float* __restrict__ ws, float* __restrict__ out) {
  __shared__ double red[16][8];  // 16 waves x 6 sums (padded)
  const int tid = threadIdx.x;
  const int lane = tid & 63, wid = tid >> 6;

  double acc[6] = {0, 0, 0, 0, 0, 0};
#pragma unroll
  for (int k = 0; k < 5; ++k)
    for (int i = tid; i < BB; i += 1024)
      acc[k] += (double)ws[k * PB_STRIDE + i];
  for (int i = tid; i < MORGAN_BLOCKS; i += 1024)
    acc[5] += (double)ws[PBM_OFF + i];

#pragma unroll
  for (int k = 0; k < 6; ++k) acc[k] = waveReduceD(acc[k]);
  if (lane == 0) {
#pragma unroll
    for (int k = 0; k < 6; ++k) red[wid][k] = acc[k];
  }
  __syncthreads();
  if (tid == 0) {
    double t[6];
#pragma unroll
    for (int k = 0; k < 6; ++k) {
      double s = 0.0;
      for (int w = 0; w < 16; ++w) s += red[w][k];
      t[k] = s;
    }
    const double prob = t[0] / ((double)BB * (double)MZ);
    const double inten = t[1] / (t[2] + (double)EPSF);
    const double nv = t[4];
    const double ws_loss = (nv > 0.0) ? (t[3] / fmax(nv, 1.0)) : 0.0;
    const double morgan = t[5] / ((double)BB * (double)NF);
    double tot = (double)W_PROB * prob + (double)W_INT * inten +
                 (double)W_WS * ws_loss + (double)W_MORGAN * morgan;
    float r = (float)tot;
    if (isnan(r) || isinf(r)) r = 100000.0f;
    out[0] = r;
  }
}

extern "C" void kernel_launch(void* const* d_in, const int* in_sizes, int n_in,
                              void* d_out, int out_size, void* d_ws, size_t ws_size,
                              hipStream_t stream) {
  const float* pred_int = (const float*)d_in[0];
  const float* pred_pl  = (const float*)d_in[1];
  const float* pred_mg  = (const float*)d_in[2];
  const float* true_int = (const float*)d_in[3];
  const float* true_pr  = (const float*)d_in[4];
  const int*   true_mg  = (const int*)d_in[5];
  float* ws = (float*)d_ws;

  row_kernel<<<BB, 256, 0, stream>>>(pred_int, pred_pl, true_int, true_pr, ws);
  morgan_kernel<<<MORGAN_BLOCKS, 256, 0, stream>>>(pred_mg, true_mg, ws + PBM_OFF);
  reduce_finalize_kernel<<<1, 1024, 0, stream>>>(ws, (float*)d_out);
}

// Round 5
// 348.561 us; speedup vs baseline: 2.2483x; 1.1141x over previous
//
#include <hip/hip_runtime.h>
#include <cmath>

#define EPSF 1.1920928955078125e-07f

constexpr int BB = 8192;
constexpr int MZ = 2000;
constexpr int NF = 2048;
constexpr int MORGAN_BLOCKS = 2048;
constexpr int FUSED_BLOCKS = BB + MORGAN_BLOCKS;  // 10240 = 2048 groups of 5
constexpr float W_INT = 0.1f, W_PROB = 0.3f, W_WS = 0.5f, W_MORGAN = 0.1f;
constexpr float POS_W = 5.0f;

// d_ws layout (floats):
//   pb[k][row], k=0..4 : per-row partials  (5 * 8192)
//     k=0: bce*w sum   k=1: sq sum   k=2: iw sum   k=3: per*valid   k=4: valid
//   pbm[b], b=0..2047  : morgan per-block partial
constexpr int PB_STRIDE = BB;
constexpr int PBM_OFF = 5 * BB;

__device__ inline float waveReduce(float v) {
#pragma unroll
  for (int off = 32; off > 0; off >>= 1) v += __shfl_down(v, off, 64);
  return v;
}

__device__ inline double waveReduceD(double v) {
#pragma unroll
  for (int off = 32; off > 0; off >>= 1) v += __shfl_down(v, off, 64);
  return v;
}

// natives: v_exp_f32 / v_log_f32 / v_rcp_f32 — errors ~1ulp, threshold is 1.9e-2
__device__ inline float bceFast(float x, float y) {
  const float em = __expf(-fabsf(x));
  return fmaxf(x, 0.f) - x * y + __logf(1.f + em);
}

__device__ inline void row_body(int bid, const float* __restrict__ pi,
                                const float* __restrict__ pl,
                                const float* __restrict__ ti,
                                const float* __restrict__ tp,
                                float* __restrict__ pb) {
  __shared__ float red[4][8];   // per-wave partials (5 used)
  __shared__ float bc[2];       // s1, st1 broadcast
  __shared__ float wtot[4];     // per-wave scan totals

  const int tid = threadIdx.x;
  const int lane = tid & 63;
  const int wid = tid >> 6;
  const long base = (long)bid * MZ;
  const int i0 = tid * 8;

  float a[8], b[8];
  float s_bce = 0.f, s_sq = 0.f, s_iw = 0.f, la = 0.f, lb = 0.f;

  if (i0 + 8 <= MZ) {  // MZ = 250*8: threads 0..249 take the full vector path
    const float4* ppi = (const float4*)(pi + base + i0);
    const float4* ppl = (const float4*)(pl + base + i0);
    const float4* pti = (const float4*)(ti + base + i0);
    const float4* ptp = (const float4*)(tp + base + i0);
    float4 vpi0 = ppi[0], vpi1 = ppi[1];
    float4 vpl0 = ppl[0], vpl1 = ppl[1];
    float4 vti0 = pti[0], vti1 = pti[1];
    float4 vtp0 = ptp[0], vtp1 = ptp[1];
    float xpi[8] = {vpi0.x, vpi0.y, vpi0.z, vpi0.w, vpi1.x, vpi1.y, vpi1.z, vpi1.w};
    float xpl[8] = {vpl0.x, vpl0.y, vpl0.z, vpl0.w, vpl1.x, vpl1.y, vpl1.z, vpl1.w};
    float xti[8] = {vti0.x, vti0.y, vti0.z, vti0.w, vti1.x, vti1.y, vti1.z, vti1.w};
    float xtp[8] = {vtp0.x, vtp0.y, vtp0.z, vtp0.w, vtp1.x, vtp1.y, vtp1.z, vtp1.w};
#pragma unroll
    for (int j = 0; j < 8; ++j) {
      const float x = xpl[j];
      const float y = xtp[j];
      const float em = __expf(-fabsf(x));        // v_exp_f32, shared by bce+sigmoid
      const float bce = fmaxf(x, 0.f) - x * y + __logf(1.f + em);  // v_log_f32
      const bool pos = (y > 0.5f);
      s_bce += bce * (pos ? POS_W : 1.f);
      const float d = xpi[j] - xti[j];
      if (pos) { s_sq = fmaf(d, d, s_sq); s_iw += 1.f; }
      const float inv = __builtin_amdgcn_rcpf(1.f + em);  // v_rcp_f32
      const float sig = (x >= 0.f) ? inv : em * inv;
      const float av = fmaxf(xpi[j], 0.f) * sig;
      const float bv = xti[j] * y;
      a[j] = av; b[j] = bv;
      la += av; lb += bv;
    }
  } else {
#pragma unroll
    for (int j = 0; j < 8; ++j) { a[j] = 0.f; b[j] = 0.f; }
  }

  // fused block-reduce of 5 partials (1 barrier, shuffles otherwise)
  float v0 = waveReduce(la);
  float v1 = waveReduce(lb);
  float v2 = waveReduce(s_bce);
  float v3 = waveReduce(s_sq);
  float v4 = waveReduce(s_iw);
  if (lane == 0) {
    red[wid][0] = v0; red[wid][1] = v1; red[wid][2] = v2;
    red[wid][3] = v3; red[wid][4] = v4;
  }
  __syncthreads();
  if (tid == 0) {
    const float s1  = red[0][0] + red[1][0] + red[2][0] + red[3][0];
    const float st1 = red[0][1] + red[1][1] + red[2][1] + red[3][1];
    bc[0] = s1; bc[1] = st1;
    // plain stores of the three streaming partials (no atomics)
    pb[0 * PB_STRIDE + bid] = red[0][2] + red[1][2] + red[2][2] + red[3][2];
    pb[1 * PB_STRIDE + bid] = red[0][3] + red[1][3] + red[2][3] + red[3][3];
    pb[2 * PB_STRIDE + bid] = red[0][4] + red[1][4] + red[2][4] + red[3][4];
  }
  __syncthreads();
  const float s1 = bc[0], st1 = bc[1];

  // replicate jnp's double renormalization analytically
  const float s2 = s1 / (s1 + EPSF);
  const float scaleP = 1.f / ((s1 + EPSF) * (s2 + EPSF));
  const float st2 = st1 / (st1 + EPSF);
  const float scaleQ = 1.f / ((st1 + EPSF) * (st2 + EPSF));

  // in-register chunk prefix of (p - q)
  float run = 0.f;
#pragma unroll
  for (int j = 0; j < 8; ++j) {
    run += a[j] * scaleP - b[j] * scaleQ;
    a[j] = run;  // a[] now holds the inclusive chunk prefix
  }

  // per-wave inclusive scan of chunk totals (no barriers)
  float sc = run;
#pragma unroll
  for (int off = 1; off < 64; off <<= 1) {
    const float t = __shfl_up(sc, off, 64);
    if (lane >= off) sc += t;
  }
  if (lane == 63) wtot[wid] = sc;   // wave total
  __syncthreads();
  float woff = 0.f;
#pragma unroll
  for (int w = 0; w < 4; ++w) woff += (w < wid) ? wtot[w] : 0.f;
  const float excl = sc - run + woff;  // exclusive prefix for this thread

  // |cdf| sum, excluding last grid point (index MZ-1)
  float labs = 0.f;
#pragma unroll
  for (int j = 0; j < 8; ++j) {
    if (i0 + j < MZ - 1) labs += fabsf(excl + a[j]);
  }
  labs = waveReduce(labs);
  if (lane == 0) red[wid][0] = labs;
  __syncthreads();
  if (tid == 0) {
    const float t = red[0][0] + red[1][0] + red[2][0] + red[3][0];
    const float w1 = t * (1.f / (1999.0f + EPSF));
    const float psum = s2 / (s2 + EPSF);
    const float qsum = st2 / (st2 + EPSF);
    const float valid = (qsum > EPSF) ? 1.f : 0.f;
    const float per = (psum > EPSF) ? w1 : 1.f;
    pb[3 * PB_STRIDE + bid] = per * valid;
    pb[4 * PB_STRIDE + bid] = valid;
  }
}

__device__ inline void morgan_body(int mbid, const float* __restrict__ x,
                                   const int* __restrict__ y,
                                   float* __restrict__ pbm) {
  __shared__ float mred[4];
  const long n4 = (long)BB * NF / 4;
  const long stride = (long)MORGAN_BLOCKS * 256;
  float ls = 0.f;
  for (long i = (long)mbid * 256 + threadIdx.x; i < n4; i += stride) {
    const float4 xv = ((const float4*)x)[i];
    const int4 yv = ((const int4*)y)[i];
    ls += bceFast(xv.x, (float)yv.x);
    ls += bceFast(xv.y, (float)yv.y);
    ls += bceFast(xv.z, (float)yv.z);
    ls += bceFast(xv.w, (float)yv.w);
  }
  ls = waveReduce(ls);
  const int lane = threadIdx.x & 63, wid = threadIdx.x >> 6;
  if (lane == 0) mred[wid] = ls;
  __syncthreads();
  if (threadIdx.x == 0)
    pbm[mbid] = mred[0] + mred[1] + mred[2] + mred[3];
}

// one launch, 4:1 interleave: each group of 5 blocks = 4 rows + 1 morgan slice
__global__ __launch_bounds__(256) void fused_kernel(
    const float* __restrict__ pi, const float* __restrict__ pl,
    const float* __restrict__ ti, const float* __restrict__ tp,
    const float* __restrict__ mx, const int* __restrict__ my,
    float* __restrict__ ws) {
  const int q = blockIdx.x / 5;
  const int r = blockIdx.x % 5;
  if (r < 4) {
    row_body(q * 4 + r, pi, pl, ti, tp, ws);
  } else {
    morgan_body(q, mx, my, ws + PBM_OFF);
  }
}

__global__ __launch_bounds__(1024) void reduce_finalize_kernel(
    const float* __restrict__ ws, float* __restrict__ out) {
  __shared__ double red[16][8];  // 16 waves x 6 sums (padded)
  const int tid = threadIdx.x;
  const int lane = tid & 63, wid = tid >> 6;

  double acc[6] = {0, 0, 0, 0, 0, 0};
#pragma unroll
  for (int k = 0; k < 5; ++k) {
    const float4* v = (const float4*)(ws + k * PB_STRIDE);
    for (int i = tid; i < BB / 4; i += 1024) {
      const float4 f = v[i];
      acc[k] += (double)f.x + (double)f.y + (double)f.z + (double)f.w;
    }
  }
  {
    const float4* v = (const float4*)(ws + PBM_OFF);
    for (int i = tid; i < MORGAN_BLOCKS / 4; i += 1024) {
      const float4 f = v[i];
      acc[5] += (double)f.x + (double)f.y + (double)f.z + (double)f.w;
    }
  }

#pragma unroll
  for (int k = 0; k < 6; ++k) acc[k] = waveReduceD(acc[k]);
  if (lane == 0) {
#pragma unroll
    for (int k = 0; k < 6; ++k) red[wid][k] = acc[k];
  }
  __syncthreads();
  if (tid == 0) {
    double t[6];
#pragma unroll
    for (int k = 0; k < 6; ++k) {
      double s = 0.0;
      for (int w = 0; w < 16; ++w) s += red[w][k];
      t[k] = s;
    }
    const double prob = t[0] / ((double)BB * (double)MZ);
    const double inten = t[1] / (t[2] + (double)EPSF);
    const double nv = t[4];
    const double ws_loss = (nv > 0.0) ? (t[3] / fmax(nv, 1.0)) : 0.0;
    const double morgan = t[5] / ((double)BB * (double)NF);
    double tot = (double)W_PROB * prob + (double)W_INT * inten +
                 (double)W_WS * ws_loss + (double)W_MORGAN * morgan;
    float r = (float)tot;
    if (isnan(r) || isinf(r)) r = 100000.0f;
    out[0] = r;
  }
}

extern "C" void kernel_launch(void* const* d_in, const int* in_sizes, int n_in,
                              void* d_out, int out_size, void* d_ws, size_t ws_size,
                              hipStream_t stream) {
  const float* pred_int = (const float*)d_in[0];
  const float* pred_pl  = (const float*)d_in[1];
  const float* pred_mg  = (const float*)d_in[2];
  const float* true_int = (const float*)d_in[3];
  const float* true_pr  = (const float*)d_in[4];
  const int*   true_mg  = (const int*)d_in[5];
  float* ws = (float*)d_ws;

  fused_kernel<<<FUSED_BLOCKS, 256, 0, stream>>>(
      pred_int, pred_pl, true_int, true_pr, pred_mg, true_mg, ws);
  reduce_finalize_kernel<<<1, 1024, 0, stream>>>(ws, (float*)d_out);
}